// Round 8
// baseline (61.686 us; speedup 1.0000x reference)
//
#include <hip/hip_runtime.h>
#include <math.h>

#define KW 11
#define HALO 10
#define TY 16
#define BATCH 32
#define HH 512
#define WW 512
#define OH 502
#define OW 502
#define NSX 8          // 8 strips x 64 cols
#define WPB 2          // independent waves per block (no __syncthreads)
#define NBX 4
#define NBY 32         // ceil(502/16)
#define NWAVE (BATCH * NBY * NSX)
#define C3V 1.0e-4f
#define SW 80          // staged cols per row (64 + 16 halo), one v2f (a,b) each

typedef float v2f __attribute__((ext_vector_type(2)));

static __device__ __forceinline__ float rfl(float x) {
    return __int_as_float(__builtin_amdgcn_readfirstlane(__float_as_int(x)));
}

// 2 independent waves/block. Each wave: 64-col strip, TY=16 output rows (26
// input rows) through an 11-slot wave-private LDS ring of interleaved (a,b)
// rows. Packed-f32 math. Phase body (consume-then-refill):
//   1) h-conv from window regs W (row yr)
//   2) ds_write row yr+1 -> slot p+1   3) ds_read slot p+1 -> W
//   4) global prefetch row yr+2        5) v-conv + fused epilogue
// TY=16 doubles wave count (8192) -> ~22 resident waves/CU (LDS-capped),
// covering the lgkm/vm stalls that capped R7 at 58% VALUBusy.
__global__ __launch_bounds__(128) void ssim_strip_kernel(
    const float* __restrict__ in1,
    const float* __restrict__ in2,
    const float* __restrict__ win,
    double* __restrict__ partials)
{
    __shared__ v2f sh[WPB][KW][SW];   // 14080 B

    const int t = threadIdx.x;
    const int wid = t >> 6;
    const int lane = t & 63;
    const int strip = blockIdx.x * WPB + wid;
    const int x0 = strip * 64;
    const int y0 = blockIdx.y * TY;
    const int img = blockIdx.z;

    const int nx = min(64, OW - x0);     // 64, last strip 54
    const int ny = min(TY, OH - y0);     // 16, last y-strip 6
    const int rows = ny + HALO;          // 26 or 16

    // separable 1D gaussian; symmetric: g[j] == g[10-j] -> 6 unique splats
    v2f gp[6];
    {
        const float c = sqrtf(win[5 * KW + 5]);
        #pragma unroll
        for (int i = 0; i < 6; ++i) {
            const float w = rfl(win[i * KW + 5] / c);
            gp[i] = (v2f){w, w};
        }
    }
    #define GW(j) gp[(j) <= 5 ? (j) : 10 - (j)]

    const float maskf = (lane < nx) ? 1.f : 0.f;
    const bool stager = lane < 40;                    // 40 lanes x 2 cols = 80
    const int scol = min(x0 + 2 * lane, WW - 2);      // clamped: no OOB
    const float* b1 = in1 + (size_t)img * HH * WW;
    const float* b2 = in2 + (size_t)img * HH * WW;

    v2f* const mysh = &sh[wid][0][0];                 // slot stride = SW v2f

    v2f va, vb;
#define LOADR(q) { const int rq = min(y0 + (q), HH - 1);             \
    va = *(const v2f*)(b1 + (size_t)rq * WW + scol);                 \
    vb = *(const v2f*)(b2 + (size_t)rq * WW + scol); }
#define WRITES(slot) { if (stager)                                    \
    *(float4*)&mysh[(slot) * SW + 2 * lane] =                         \
        make_float4(va.x, vb.x, va.y, vb.y); }
#define RDWIN(slot) { _Pragma("unroll")                               \
    for (int j = 0; j < KW; ++j) W[j] = mysh[(slot) * SW + lane + j]; }

    // vertical accumulators: (a,b) packed, (aa,bb) packed, ab scalar
    v2f accab[KW], accsq[KW];
    float acc4[KW];
    #pragma unroll
    for (int i = 0; i < KW; ++i) {
        accab[i] = (v2f){0.f, 0.f}; accsq[i] = (v2f){0.f, 0.f}; acc4[i] = 0.f;
    }

    v2f W[KW];
    double tsum = 0.0;

    // prologue: row 0 staged + window loaded; row 1 in staging regs
    LOADR(0);
    WRITES(0);
    RDWIN(0);
    LOADR(1);

    for (int c = 0; c < 3; ++c) {        // up to 33 phases; guarded past `rows`
        float csum = 0.f;
        #pragma unroll
        for (int p = 0; p < KW; ++p) {
            const int yr = c * KW + p;
            if (yr < rows) {             // wave-uniform guard
                // 1) horizontal 11-tap conv from W (row yr), packed channels
                v2f hab = (v2f){0.f, 0.f}, hsq = (v2f){0.f, 0.f};
                float h4 = 0.f;
                #pragma unroll
                for (int j = 0; j < KW; ++j) {
                    const v2f ab = W[j];
                    const v2f g = GW(j);
                    const v2f gab = g * ab;                              // pk_mul
                    hab = __builtin_elementwise_fma(g, ab, hab);         // pk_fma
                    hsq = __builtin_elementwise_fma(gab, ab, hsq);       // pk_fma
                    h4 = fmaf(gab.x, ab.y, h4);                          // scalar
                }

                // 2) stage row yr+1 (loaded last phase) into slot p+1
                WRITES((p + 1) % KW);
                // 3) refill W with row yr+1's window (latency covered by 5)
                RDWIN((p + 1) % KW);
                // 4) global prefetch row yr+2
                LOADR(yr + 2);

                // 5) vertical accumulate: slot j lives in register (j+p)%11;
                //    slot 10 is the first tap -> overwrite (no reset)
                #pragma unroll
                for (int r = 0; r < KW; ++r) {
                    const int j = (r - p + KW) % KW;
                    const v2f g = GW(10 - j);
                    if (j == 10) {
                        accab[r] = g * hab;
                        accsq[r] = g * hsq;
                        acc4[r] = g.x * h4;
                    } else {
                        accab[r] = __builtin_elementwise_fma(g, hab, accab[r]);
                        accsq[r] = __builtin_elementwise_fma(g, hsq, accsq[r]);
                        acc4[r] = fmaf(g.x, h4, acc4[r]);
                    }
                }
                // register p completes -> output row yr-10 (uniform branch)
                if (yr >= HALO) {
                    const v2f mu = accab[p];
                    const v2f sq = __builtin_elementwise_fma(-mu, mu, accsq[p]);
                    const float s12 = fmaf(-mu.x, mu.y, acc4[p]);
                    const float den = __builtin_amdgcn_sqrtf(fabsf(sq.x * sq.y)) + C3V;
                    const float s = (s12 + C3V) * __builtin_amdgcn_rcpf(den);
                    const float m = ((yr - HALO) < ny) ? maskf : 0.f;
                    csum = fmaf(s, m, csum);
                }
            }
        }
        tsum += (double)csum;
    }
#undef LOADR
#undef WRITES
#undef RDWIN
#undef GW

    // per-wave deterministic reduction
    #pragma unroll
    for (int off = 32; off > 0; off >>= 1)
        tsum += __shfl_down(tsum, off, 64);
    if (lane == 0) {
        const int bid = (img * NBY + blockIdx.y) * NSX + strip;
        partials[bid] = tsum;
    }
}

// deterministic final reduce of the 8192 wave partials -> mean
__global__ __launch_bounds__(256) void ssim_reduce_kernel(
    const double* __restrict__ partials, float* __restrict__ out)
{
    __shared__ double sred[4];
    double s = 0.0;
    for (int i = threadIdx.x; i < NWAVE; i += 256) s += partials[i];
    #pragma unroll
    for (int off = 32; off > 0; off >>= 1)
        s += __shfl_down(s, off, 64);
    const int wid = threadIdx.x >> 6;
    const int lane = threadIdx.x & 63;
    if (lane == 0) sred[wid] = s;
    __syncthreads();
    if (threadIdx.x == 0) {
        const double total = sred[0] + sred[1] + sred[2] + sred[3];
        out[0] = (float)(total / ((double)BATCH * OH * OW));
    }
}

extern "C" void kernel_launch(void* const* d_in, const int* in_sizes, int n_in,
                              void* d_out, int out_size, void* d_ws, size_t ws_size,
                              hipStream_t stream) {
    const float* in1 = (const float*)d_in[0];
    const float* in2 = (const float*)d_in[1];
    const float* win = (const float*)d_in[2];
    float* out = (float*)d_out;
    double* partials = (double*)d_ws;   // 8192 doubles = 64 KB

    dim3 grid(NBX, NBY, BATCH);
    dim3 block(WPB * 64);
    ssim_strip_kernel<<<grid, block, 0, stream>>>(in1, in2, win, partials);
    ssim_reduce_kernel<<<1, 256, 0, stream>>>(partials, out);
}

// Round 9
// 54.403 us; speedup vs baseline: 1.1339x; 1.1339x over previous
//
#include <hip/hip_runtime.h>
#include <math.h>

#define KW 11
#define HALO 10
#define TY 32
#define BATCH 32
#define HH 512
#define WW 512
#define OH 502
#define OW 502
#define NSX 8          // 8 strips x 64 cols
#define WPB 2          // independent waves per block (no __syncthreads)
#define NBX 4
#define NBY 16
#define NWAVE (BATCH * NBY * NSX)
#define C3V 1.0e-4f
#define SW 128         // slot stride in v2f: 80 data + 48 pad (absorbs lanes 40-63 stores)

typedef float v2f __attribute__((ext_vector_type(2)));

static __device__ __forceinline__ float rfl(float x) {
    return __int_as_float(__builtin_amdgcn_readfirstlane(__float_as_int(x)));
}

// 2 independent waves/block. Each wave: 64-col strip, 44 rows through an
// 11-slot wave-private LDS ring (slot stride 128 v2f; [80,128) is write pad).
// Distance-2 software pipeline, enforced by sched_group_barrier:
//   phase p: RDWIN slot p+1 -> W_next   (row yr+1; written LAST phase)
//            h-conv consumes W_cur      (row yr; read LAST phase)
//            ds_write slot p+2          (row yr+2; loaded last phase)
//            global prefetch row yr+3
//            v-conv (register-rotated) + fused epilogue
// 22-phase unrolled super-chunk keeps slot (mod 11) and W parity (mod 2)
// compile-time. Packed-f32 (v_pk_fma_f32) math throughout.
__global__ __launch_bounds__(128) void ssim_strip_kernel(
    const float* __restrict__ in1,
    const float* __restrict__ in2,
    const float* __restrict__ win,
    double* __restrict__ partials)
{
    __shared__ v2f sh[WPB][KW * SW];   // 22528 B

    const int t = threadIdx.x;
    const int wid = t >> 6;
    const int lane = t & 63;
    const int strip = blockIdx.x * WPB + wid;
    const int x0 = strip * 64;
    const int y0 = blockIdx.y * TY;
    const int img = blockIdx.z;

    const int nx = min(64, OW - x0);     // 64, last strip 54
    const int ny = min(TY, OH - y0);     // 32, last y-strip 22

    // separable 1D gaussian; symmetric: g[j] == g[10-j] -> 6 unique splats
    v2f gp[6];
    {
        const float c = sqrtf(win[5 * KW + 5]);
        #pragma unroll
        for (int i = 0; i < 6; ++i) {
            const float w = rfl(win[i * KW + 5] / c);
            gp[i] = (v2f){w, w};
        }
    }
    #define GW(j) gp[(j) <= 5 ? (j) : 10 - (j)]

    const float maskf = (lane < nx) ? 1.f : 0.f;
    const int scol = min(x0 + 2 * lane, WW - 2);      // clamped: no OOB
    const float* b1 = in1 + (size_t)img * HH * WW;
    const float* b2 = in2 + (size_t)img * HH * WW;

    v2f* const mysh = &sh[wid][0];

    v2f sva, svb;      // staging regs (single set, distance-1 load->write)
    v2f W0[KW], W1[KW];

#define LOADR(q) { const int rq = min(y0 + (q), HH - 1);               \
    sva = *(const v2f*)(b1 + (size_t)rq * WW + scol);                  \
    svb = *(const v2f*)(b2 + (size_t)rq * WW + scol); }
    // all 64 lanes store; lanes 40-63 land in the [80,128) pad of the slot
#define WRITES(slot) {                                                  \
    *(float4*)&mysh[(slot) * SW + 2 * lane] =                           \
        make_float4(sva.x, svb.x, sva.y, svb.y); }
#define RDWIN(slot, Warr) { const v2f* rp = mysh + (slot) * SW + lane;  \
    _Pragma("unroll") for (int j = 0; j < KW; ++j) Warr[j] = rp[j]; }
#define HCONV(Warr) {                                                   \
    _Pragma("unroll") for (int j = 0; j < KW; ++j) {                    \
        const v2f ab = Warr[j];                                         \
        const v2f g = GW(j);                                            \
        const v2f gab = g * ab;                                         \
        hab = __builtin_elementwise_fma(g, ab, hab);                    \
        hsq = __builtin_elementwise_fma(gab, ab, hsq);                  \
        h4 = fmaf(gab.x, ab.y, h4); } }

    // vertical accumulators: (a,b) packed, (aa,bb) packed, ab scalar
    v2f accab[KW], accsq[KW];
    float acc4[KW];
    #pragma unroll
    for (int i = 0; i < KW; ++i) {
        accab[i] = (v2f){0.f, 0.f}; accsq[i] = (v2f){0.f, 0.f}; acc4[i] = 0.f;
    }

    double tsum = 0.0;

    // prologue: slots 0,1 = rows 0,1; W0 = row 0 window; S = row 2
    LOADR(0); WRITES(0);
    LOADR(1); WRITES(1);
    RDWIN(0, W0);
    LOADR(2);

    for (int c = 0; c < 2; ++c) {        // 2 x 22 phases = 44 rows
        const int cbase = c * 22;
        float csum = 0.f;
        #pragma unroll
        for (int p = 0; p < 22; ++p) {
            const int pe = p % KW;       // compile-time after unroll
            const int yr = cbase + p;    // uniform runtime

            // 1) read NEXT row's window (slot written last phase)
            if ((p & 1) == 0) { RDWIN((pe + 1) % KW, W1); }
            else              { RDWIN((pe + 1) % KW, W0); }
            __builtin_amdgcn_sched_group_barrier(0x100, 11, 0);  // DS_READ x11

            // 2) h-conv from CURRENT window (read a full phase ago)
            v2f hab = (v2f){0.f, 0.f}, hsq = (v2f){0.f, 0.f};
            float h4 = 0.f;
            if ((p & 1) == 0) { HCONV(W0); } else { HCONV(W1); }
            __builtin_amdgcn_sched_group_barrier(0x2, 40, 0);    // VALU x40

            // 3) stage row yr+2 (loaded last phase) into slot p+2
            WRITES((pe + 2) % KW);
            __builtin_amdgcn_sched_group_barrier(0x200, 1, 0);   // DS_WRITE x1

            // 4) global prefetch row yr+3
            LOADR(yr + 3);
            __builtin_amdgcn_sched_group_barrier(0x20, 2, 0);    // VMEM_READ x2

            // 5) vertical accumulate: slot j lives in register (j+pe)%11;
            //    slot 10 is the first tap -> overwrite (no reset)
            #pragma unroll
            for (int r = 0; r < KW; ++r) {
                const int j = (r - pe + KW) % KW;
                const v2f g = GW(10 - j);
                if (j == 10) {
                    accab[r] = g * hab;
                    accsq[r] = g * hsq;
                    acc4[r] = g.x * h4;
                } else {
                    accab[r] = __builtin_elementwise_fma(g, hab, accab[r]);
                    accsq[r] = __builtin_elementwise_fma(g, hsq, accsq[r]);
                    acc4[r] = fmaf(g.x, h4, acc4[r]);
                }
            }
            // register pe completes -> output row yr-10; branchless mask
            const v2f mu = accab[pe];
            const v2f sq = __builtin_elementwise_fma(-mu, mu, accsq[pe]);
            const float s12 = fmaf(-mu.x, mu.y, acc4[pe]);
            const float den = __builtin_amdgcn_sqrtf(fabsf(sq.x * sq.y)) + C3V;
            const float s = (s12 + C3V) * __builtin_amdgcn_rcpf(den);
            const float m = ((unsigned)(yr - HALO) < (unsigned)ny) ? maskf : 0.f;
            csum = fmaf(s, m, csum);
        }
        tsum += (double)csum;
    }
#undef LOADR
#undef WRITES
#undef RDWIN
#undef HCONV
#undef GW

    // per-wave deterministic reduction
    #pragma unroll
    for (int off = 32; off > 0; off >>= 1)
        tsum += __shfl_down(tsum, off, 64);
    if (lane == 0) {
        const int bid = (img * NBY + blockIdx.y) * NSX + strip;
        partials[bid] = tsum;
    }
}

// deterministic final reduce of the 4096 wave partials -> mean
__global__ __launch_bounds__(256) void ssim_reduce_kernel(
    const double* __restrict__ partials, float* __restrict__ out)
{
    __shared__ double sred[4];
    double s = 0.0;
    for (int i = threadIdx.x; i < NWAVE; i += 256) s += partials[i];
    #pragma unroll
    for (int off = 32; off > 0; off >>= 1)
        s += __shfl_down(s, off, 64);
    const int wid = threadIdx.x >> 6;
    const int lane = threadIdx.x & 63;
    if (lane == 0) sred[wid] = s;
    __syncthreads();
    if (threadIdx.x == 0) {
        const double total = sred[0] + sred[1] + sred[2] + sred[3];
        out[0] = (float)(total / ((double)BATCH * OH * OW));
    }
}

extern "C" void kernel_launch(void* const* d_in, const int* in_sizes, int n_in,
                              void* d_out, int out_size, void* d_ws, size_t ws_size,
                              hipStream_t stream) {
    const float* in1 = (const float*)d_in[0];
    const float* in2 = (const float*)d_in[1];
    const float* win = (const float*)d_in[2];
    float* out = (float*)d_out;
    double* partials = (double*)d_ws;   // 4096 doubles = 32 KB

    dim3 grid(NBX, NBY, BATCH);
    dim3 block(WPB * 64);
    ssim_strip_kernel<<<grid, block, 0, stream>>>(in1, in2, win, partials);
    ssim_reduce_kernel<<<1, 256, 0, stream>>>(partials, out);
}

// Round 10
// 48.913 us; speedup vs baseline: 1.2611x; 1.1122x over previous
//
#include <hip/hip_runtime.h>
#include <math.h>

#define KW 11
#define HALO 10
#define TY 32
#define BATCH 32
#define HH 512
#define WW 512
#define OH 502
#define OW 502
#define SPW 128        // strip width: output cols per wave (2 per lane)
#define NSX 4          // 4 strips x 128 = 512
#define WPB 2          // independent waves per block (no __syncthreads)
#define NBX 2
#define NBY 16
#define NWAVE (BATCH * NBY * NSX)   // 2048
#define C3V 1.0e-4f
#define SW 144         // slot stride in v2f: 138 data + 6 pad (16B-aligned slots)

typedef float v2f __attribute__((ext_vector_type(2)));

static __device__ __forceinline__ float rfl(float x) {
    return __int_as_float(__builtin_amdgcn_readfirstlane(__float_as_int(x)));
}

// 2 independent waves/block; each wave owns a 128-col strip (2 cols/lane).
// 44 rows stream through an 11-slot wave-private LDS ring of interleaved
// (a,b) rows. Per phase: read 12-v2f window as 6 ds_read_b128 (shared by
// both output cols), shared squares, packed-f32 h-conv, two register-rotated
// vertical accumulator sets (A,B = independent ILP chains), fused epilogue.
__global__ __launch_bounds__(128) void ssim_strip_kernel(
    const float* __restrict__ in1,
    const float* __restrict__ in2,
    const float* __restrict__ win,
    double* __restrict__ partials)
{
    __shared__ v2f sh[WPB][KW][SW];   // 25344 B

    const int t = threadIdx.x;
    const int wid = t >> 6;
    const int lane = t & 63;
    const int strip = blockIdx.x * WPB + wid;
    const int x0 = strip * SPW;
    const int y0 = blockIdx.y * TY;
    const int img = blockIdx.z;

    const int ny = min(TY, OH - y0);     // 32, last y-strip 22
    const int rows = ny + HALO;          // 42 or 32

    // separable 1D gaussian; symmetric: g[j] == g[10-j] -> 6 unique splats
    v2f gp[6];
    {
        const float c = sqrtf(win[5 * KW + 5]);
        #pragma unroll
        for (int i = 0; i < 6; ++i) {
            const float w = rfl(win[i * KW + 5] / c);
            gp[i] = (v2f){w, w};
        }
    }
    #define GW(j) gp[(j) <= 5 ? (j) : 10 - (j)]

    // two output cols per lane; column validity masks
    const int cA = x0 + 2 * lane;              // <= 510: always in-bounds read
    const v2f mcol = (v2f){ cA < OW ? 1.f : 0.f, (cA + 1) < OW ? 1.f : 0.f };

    const float* b1 = in1 + (size_t)img * HH * WW;
    const float* b2 = in2 + (size_t)img * HH * WW;
    const int hc = min(x0 + SPW + 2 * lane, WW - 2);   // halo cols, lanes 0..4
    const bool hstage = lane < 5;

    v2f* const mysh = &sh[wid][0][0];          // slot stride = SW v2f

    v2f va, vb, ha, hb;
#define LOADR(q) { const int rq = min(y0 + (q), HH - 1);                  \
    const float* r1 = b1 + (size_t)rq * WW;                               \
    const float* r2 = b2 + (size_t)rq * WW;                               \
    va = *(const v2f*)(r1 + cA); vb = *(const v2f*)(r2 + cA);             \
    if (hstage) { ha = *(const v2f*)(r1 + hc); hb = *(const v2f*)(r2 + hc); } }
#define WRITES(slot) {                                                     \
    *(float4*)&mysh[(slot) * SW + 2 * lane] =                              \
        make_float4(va.x, vb.x, va.y, vb.y);                               \
    if (hstage) *(float4*)&mysh[(slot) * SW + SPW + 2 * lane] =            \
        make_float4(ha.x, hb.x, ha.y, hb.y); }

    v2f W[12];
#define RDWIN(slot) { const v2f* rp = mysh + (slot) * SW + 2 * lane;       \
    _Pragma("unroll") for (int j = 0; j < 6; ++j)                          \
        *(float4*)&W[2 * j] = *(const float4*)&rp[2 * j]; }

    // vertical accumulators, per column: (a,b) pk, (aa,bb) pk, ab scalar
    v2f aabA[KW], asqA[KW], aabB[KW], asqB[KW];
    float a4A[KW], a4B[KW];
    #pragma unroll
    for (int i = 0; i < KW; ++i) {
        aabA[i] = (v2f){0.f, 0.f}; asqA[i] = (v2f){0.f, 0.f}; a4A[i] = 0.f;
        aabB[i] = (v2f){0.f, 0.f}; asqB[i] = (v2f){0.f, 0.f}; a4B[i] = 0.f;
    }

    double tsum = 0.0;

    // prologue: row 0 staged; row 1 in staging regs
    LOADR(0);
    WRITES(0);
    LOADR(1);

    for (int c = 0; c < 4; ++c) {        // 44 phases; guarded past `rows`
        v2f csum = (v2f){0.f, 0.f};
        #pragma unroll
        for (int p = 0; p < KW; ++p) {
            const int yr = c * KW + p;
            if (yr < rows) {             // wave-uniform guard
                RDWIN(p);                        // row yr window (12 v2f)
                WRITES((p + 1) % KW);            // row yr+1 (loaded last phase)
                LOADR(yr + 2);                   // prefetch row yr+2

                // shared squares + dual h-conv (colA taps 0-10, colB taps 1-11)
                v2f habA = (v2f){0.f, 0.f}, hsqA = (v2f){0.f, 0.f};
                v2f habB = (v2f){0.f, 0.f}, hsqB = (v2f){0.f, 0.f};
                float h4A = 0.f, h4B = 0.f;
                #pragma unroll
                for (int j = 0; j < 12; ++j) {
                    const v2f ab = W[j];
                    const v2f sq = ab * ab;            // pk_mul, shared
                    const float p4 = ab.x * ab.y;      // mul, shared
                    if (j < 11) {
                        const v2f g = GW(j);
                        habA = __builtin_elementwise_fma(g, ab, habA);
                        hsqA = __builtin_elementwise_fma(g, sq, hsqA);
                        h4A = fmaf(g.x, p4, h4A);
                    }
                    if (j > 0) {
                        const v2f g = GW(j - 1);
                        habB = __builtin_elementwise_fma(g, ab, habB);
                        hsqB = __builtin_elementwise_fma(g, sq, hsqB);
                        h4B = fmaf(g.x, p4, h4B);
                    }
                }

                // vertical accumulate, both cols: slot j -> register (j+p)%11;
                // slot 10 is the first tap -> overwrite (no reset)
                #pragma unroll
                for (int r = 0; r < KW; ++r) {
                    const int j = (r - p + KW) % KW;
                    const v2f g = GW(10 - j);
                    if (j == 10) {
                        aabA[r] = g * habA; asqA[r] = g * hsqA; a4A[r] = g.x * h4A;
                        aabB[r] = g * habB; asqB[r] = g * hsqB; a4B[r] = g.x * h4B;
                    } else {
                        aabA[r] = __builtin_elementwise_fma(g, habA, aabA[r]);
                        asqA[r] = __builtin_elementwise_fma(g, hsqA, asqA[r]);
                        a4A[r] = fmaf(g.x, h4A, a4A[r]);
                        aabB[r] = __builtin_elementwise_fma(g, habB, aabB[r]);
                        asqB[r] = __builtin_elementwise_fma(g, hsqB, asqB[r]);
                        a4B[r] = fmaf(g.x, h4B, a4B[r]);
                    }
                }

                // register p completes -> output row yr-10 (wave-uniform)
                if (yr >= HALO && (yr - HALO) < ny) {
                    const v2f muA = aabA[p], muB = aabB[p];
                    const v2f sqA = __builtin_elementwise_fma(-muA, muA, asqA[p]);
                    const v2f sqB = __builtin_elementwise_fma(-muB, muB, asqB[p]);
                    const float s12A = fmaf(-muA.x, muA.y, a4A[p]);
                    const float s12B = fmaf(-muB.x, muB.y, a4B[p]);
                    const float dA = __builtin_amdgcn_sqrtf(fabsf(sqA.x * sqA.y)) + C3V;
                    const float dB = __builtin_amdgcn_sqrtf(fabsf(sqB.x * sqB.y)) + C3V;
                    const v2f s2 = (v2f){ (s12A + C3V) * __builtin_amdgcn_rcpf(dA),
                                          (s12B + C3V) * __builtin_amdgcn_rcpf(dB) };
                    csum = __builtin_elementwise_fma(s2, mcol, csum);
                }
            }
        }
        tsum += (double)csum.x + (double)csum.y;
    }
#undef LOADR
#undef WRITES
#undef RDWIN
#undef GW

    // per-wave deterministic reduction
    #pragma unroll
    for (int off = 32; off > 0; off >>= 1)
        tsum += __shfl_down(tsum, off, 64);
    if (lane == 0) {
        const int bid = (img * NBY + blockIdx.y) * NSX + strip;
        partials[bid] = tsum;
    }
}

// deterministic final reduce of the 2048 wave partials -> mean
__global__ __launch_bounds__(256) void ssim_reduce_kernel(
    const double* __restrict__ partials, float* __restrict__ out)
{
    __shared__ double sred[4];
    double s = 0.0;
    for (int i = threadIdx.x; i < NWAVE; i += 256) s += partials[i];
    #pragma unroll
    for (int off = 32; off > 0; off >>= 1)
        s += __shfl_down(s, off, 64);
    const int wid = threadIdx.x >> 6;
    const int lane = threadIdx.x & 63;
    if (lane == 0) sred[wid] = s;
    __syncthreads();
    if (threadIdx.x == 0) {
        const double total = sred[0] + sred[1] + sred[2] + sred[3];
        out[0] = (float)(total / ((double)BATCH * OH * OW));
    }
}

extern "C" void kernel_launch(void* const* d_in, const int* in_sizes, int n_in,
                              void* d_out, int out_size, void* d_ws, size_t ws_size,
                              hipStream_t stream) {
    const float* in1 = (const float*)d_in[0];
    const float* in2 = (const float*)d_in[1];
    const float* win = (const float*)d_in[2];
    float* out = (float*)d_out;
    double* partials = (double*)d_ws;   // 2048 doubles = 16 KB

    dim3 grid(NBX, NBY, BATCH);
    dim3 block(WPB * 64);
    ssim_strip_kernel<<<grid, block, 0, stream>>>(in1, in2, win, partials);
    ssim_reduce_kernel<<<1, 256, 0, stream>>>(partials, out);
}